// Round 6
// baseline (142.216 us; speedup 1.0000x reference)
//
#include <hip/hip_runtime.h>
#include <math.h>

#define HW 4096

typedef __attribute__((ext_vector_type(8))) short short8;
typedef __attribute__((ext_vector_type(8))) _Float16 half8;
typedef __attribute__((ext_vector_type(4))) float floatx4;

// ---- bf16 helpers (round-to-nearest-even) ----
__device__ inline float bflo(unsigned u) { return __uint_as_float(u << 16); }
__device__ inline float bfhi(unsigned u) { return __uint_as_float(u & 0xffff0000u); }
__device__ inline unsigned short f2bf(float x) {
    unsigned u = __float_as_uint(x);
    return (unsigned short)((u + 0x7fffu + ((u >> 16) & 1u)) >> 16);
}
__device__ inline unsigned f2bf2(float lo, float hi) {
    unsigned a = __float_as_uint(lo), b = __float_as_uint(hi);
    a = (a + 0x7fffu + ((a >> 16) & 1u)) >> 16;
    b = (b + 0x7fffu + ((b >> 16) & 1u)) & 0xffff0000u;
    return a | b;
}
__device__ inline unsigned short f2h(float x) {
    _Float16 h = (_Float16)x;
    return __builtin_bit_cast(unsigned short, h);
}

// ws layout (bytes):
//   Wb1   @ 0        : 576*192*2    = 221184   bf16 [oc][c]
//   Wbp   @ 221184   : 192*192*2    = 73728    bf16 [oc][c]
//   xT    @ 294912   : 2*4096*192*2 = 3145728  bf16 [b*px][c]
//   qkv1b @ 3440640  : 2*18*4096*32*2 = 9437184  bf16 [b][g][px][32] (pre-dw)
//   attnO @ 12877824 : 2*4096*192*2 = 3145728  bf16 [b*px][c]

// ---------------------------------------------------------------------------
// K0: fused prep. Blocks 0..383: x transpose+convert (64px x 64c padded-LDS
// tiles, conflict-free). Blocks 384..959: W1/Wp fp32 -> bf16 convert.
// ---------------------------------------------------------------------------
__global__ __launch_bounds__(256) void k_prep(const float* __restrict__ x,
    const float* __restrict__ W1, const float* __restrict__ Wp,
    unsigned short* __restrict__ xT, unsigned short* __restrict__ Wb1,
    unsigned short* __restrict__ Wbp)
{
    const int t = threadIdx.x;
    const int bx = blockIdx.x;
    if (bx >= 384) {                       // weight convert
        int idx = (bx - 384) * 256 + t;
        if (idx < 110592) Wb1[idx] = f2bf(W1[idx]);
        else Wbp[idx - 110592] = f2bf(Wp[idx - 110592]);
        return;
    }
    __shared__ float smf[64 * 65];
    const int px0 = (bx & 63) << 6;
    const int rest = bx >> 6;              // 0..5
    const int c0 = (rest % 3) << 6;
    const int b = rest / 3;
    const float* xb = x + ((size_t)(b * 192 + c0) << 12) + px0;
    const int pxl = t & 63, csub = t >> 6;
    #pragma unroll
    for (int pass = 0; pass < 16; ++pass) {
        int c = pass * 4 + csub;
        smf[pxl * 65 + c] = xb[((size_t)c << 12) + pxl];
    }
    __syncthreads();
    const int c2 = t & 31, psub = t >> 5;
    unsigned* ob = (unsigned*)xT;
    #pragma unroll
    for (int pass = 0; pass < 8; ++pass) {
        int px = pass * 8 + psub;
        unsigned v = f2bf2(smf[px * 65 + c2 * 2], smf[px * 65 + c2 * 2 + 1]);
        ob[((size_t)((b << 12) + px0 + px)) * 96 + (c0 >> 1) + c2] = v;
    }
}

// ---------------------------------------------------------------------------
// K1: QKV 1x1 conv as bf16 MFMA GEMM. M=8192(px) N=576(oc) K=192.
// ---------------------------------------------------------------------------
__global__ __launch_bounds__(256) void k_gq(const unsigned short* __restrict__ xT,
    const unsigned short* __restrict__ Wb1, const float* __restrict__ b1,
    unsigned short* __restrict__ qkv)
{
    __shared__ __align__(16) unsigned short As[64 * 200];
    __shared__ __align__(16) unsigned short Bs[64 * 200];
    const int t = threadIdx.x;
    const int m0 = blockIdx.x * 64;
    const int n0 = blockIdx.y * 64;
    #pragma unroll
    for (int pass = 0; pass < 6; ++pass) {
        int idx = pass * 256 + t;
        int m = idx / 24, c16 = idx % 24;
        *(uint4*)&As[m * 200 + c16 * 8] = *(const uint4*)&xT[(size_t)(m0 + m) * 192 + c16 * 8];
        *(uint4*)&Bs[m * 200 + c16 * 8] = *(const uint4*)&Wb1[(size_t)(n0 + m) * 192 + c16 * 8];
    }
    __syncthreads();
    const int w = t >> 6, lane = t & 63;
    const int lm = lane & 15, lq = lane >> 4;
    floatx4 acc[4] = {};
    #pragma unroll
    for (int ks = 0; ks < 6; ++ks) {
        short8 bf = *(const short8*)&Bs[(w * 16 + lm) * 200 + ks * 32 + lq * 8];
        #pragma unroll
        for (int mt = 0; mt < 4; ++mt) {
            short8 af = *(const short8*)&As[(mt * 16 + lm) * 200 + ks * 32 + lq * 8];
            acc[mt] = __builtin_amdgcn_mfma_f32_16x16x32_bf16(af, bf, acc[mt], 0, 0, 0);
        }
    }
    __syncthreads();
    const float bias = b1[n0 + w * 16 + lm];
    #pragma unroll
    for (int mt = 0; mt < 4; ++mt)
        #pragma unroll
        for (int r = 0; r < 4; ++r)
            As[(mt * 16 + lq * 4 + r) * 72 + w * 16 + lm] = f2bf(acc[mt][r] + bias);
    __syncthreads();
    #pragma unroll
    for (int pass = 0; pass < 2; ++pass) {
        int idx = pass * 256 + t;           // 64 m x 8 n-groups
        int m = idx >> 3, n8 = idx & 7;
        uint4 val = *(const uint4*)&As[m * 72 + n8 * 8];
        int mg = m0 + m;
        int b = mg >> 12, px = mg & 4095;
        int oc = n0 + n8 * 8;
        int g = oc >> 5, d = oc & 31;
        *(uint4*)&qkv[((((size_t)(b * 18 + g) << 12) + px) << 5) + d] = val;
    }
}

// ---------------------------------------------------------------------------
// K2: FUSED depthwise-3x3 + MFMA neighborhood attention.
// Block 256 = (b, head, 8x8 tile), 4 waves. dw-conv computed in staging:
//  - K/V halo: d4-split (8 lanes per halo pos, 4ch each), dw weights in
//    registers, k l2-normalized (rinv folded), K-hat bf16 -> Ks, V f16
//    transposed -> Vts (scalar b16, cheap per wave-instr count).
//  - q: each MFMA lane dw-convs its own (px, 8ch) B-frag chunk.
// Then QK (13 mfma bf16) -> mask/bias/softmax -> P f16 in LDS (aliases Ks)
// -> PV (14 mfma f16). out bf16 [b*px][c].
// LDS: union{Ks[208][40]bf16 | Ps[64][232]f16} 29696 + Vts[32][232]f16
//      14848 + wsm 3456 + bsm 384 + rpb 676 = 49060 B -> 3 blocks/CU.
// ---------------------------------------------------------------------------
__global__ __launch_bounds__(256) void k_attn(const unsigned short* __restrict__ qkv,
    const float* __restrict__ W2, const float* __restrict__ b2,
    const float* __restrict__ temp, const float* __restrict__ rpb,
    unsigned short* __restrict__ attnO)
{
    __shared__ __align__(16) char lds[49060];
    unsigned short* Ks  = (unsigned short*)lds;            // [208][40] bf16
    unsigned short* Ps  = (unsigned short*)lds;            // [64][232] f16 (alias)
    unsigned short* Vts = (unsigned short*)(lds + 29696);  // [32][232] f16
    float* wsm  = (float*)(lds + 44544);                   // [3][9][32]
    float* bsm  = (float*)(lds + 48000);                   // [3][32]
    float* rpbs = (float*)(lds + 48384);                   // [169]

    const int t = threadIdx.x;
    const int ti = blockIdx.x >> 3, tj = blockIdx.x & 7;
    const int head = blockIdx.y, b = blockIdx.z;
    const int i0 = ti * 8, j0 = tj * 8;
    const int r0 = min(max(i0 - 3, 0), 50), c0 = min(max(j0 - 3, 0), 50);
    const unsigned short* qpl = qkv + ((size_t)(b * 18 + head) << 17);
    const unsigned short* kpl = qkv + ((size_t)(b * 18 + 6 + head) << 17);
    const unsigned short* vpl = qkv + ((size_t)(b * 18 + 12 + head) << 17);

    // ---- stage dw weights (tap-major per plane), bias, rpb ----
    for (int idx = t; idx < 864; idx += 256) {
        int pl = idx / 288, rem = idx - pl * 288;
        int tap = rem >> 5, ch = rem & 31;
        wsm[idx] = W2[(pl * 192 + head * 32 + ch) * 9 + tap];
    }
    for (int idx = t; idx < 96; idx += 256)
        bsm[idx] = b2[(idx >> 5) * 192 + head * 32 + (idx & 31)];
    if (t < 169) rpbs[t] = rpb[head * 169 + t];
    __syncthreads();

    // ---- K/V halo dw staging: 8 lanes per pos (d4 = 4ch chunk) ----
    const int d4 = t & 7, slot = t >> 3;
    {
        float4 wk4[9], wv4[9];
        #pragma unroll
        for (int tap = 0; tap < 9; ++tap) {
            wk4[tap] = *(const float4*)&wsm[288 + tap * 32 + d4 * 4];
            wv4[tap] = *(const float4*)&wsm[576 + tap * 32 + d4 * 4];
        }
        const float4 bk4 = *(const float4*)&bsm[32 + d4 * 4];
        const float4 bv4 = *(const float4*)&bsm[64 + d4 * 4];
        #pragma unroll
        for (int ph = 0; ph < 7; ++ph) {
            int p = slot + ph * 32;
            bool act = p < 196;
            float4 sk = bk4, sv = bv4;
            if (act) {
                int r = (p * 2341) >> 15, cc = p - r * 14;
                int gi = r0 + r, gj = c0 + cc;
                #pragma unroll
                for (int di = -1; di <= 1; ++di) {
                    int ii = gi + di;
                    if (ii < 0 || ii > 63) continue;
                    #pragma unroll
                    for (int dj = -1; dj <= 1; ++dj) {
                        int jj = gj + dj;
                        if (jj < 0 || jj > 63) continue;
                        int tap = (di + 1) * 3 + dj + 1;
                        size_t off = ((size_t)((ii << 6) + jj) << 5) + d4 * 4;
                        uint2 ku = *(const uint2*)(kpl + off);
                        uint2 vu = *(const uint2*)(vpl + off);
                        sk.x = fmaf(bflo(ku.x), wk4[tap].x, sk.x);
                        sk.y = fmaf(bfhi(ku.x), wk4[tap].y, sk.y);
                        sk.z = fmaf(bflo(ku.y), wk4[tap].z, sk.z);
                        sk.w = fmaf(bfhi(ku.y), wk4[tap].w, sk.w);
                        sv.x = fmaf(bflo(vu.x), wv4[tap].x, sv.x);
                        sv.y = fmaf(bfhi(vu.x), wv4[tap].y, sv.y);
                        sv.z = fmaf(bflo(vu.y), wv4[tap].z, sv.z);
                        sv.w = fmaf(bfhi(vu.y), wv4[tap].w, sv.w);
                    }
                }
            }
            float ss = act ? (sk.x*sk.x + sk.y*sk.y + sk.z*sk.z + sk.w*sk.w) : 0.f;
            ss += __shfl_xor(ss, 1);
            ss += __shfl_xor(ss, 2);
            ss += __shfl_xor(ss, 4);
            if (act) {
                float rinv = 1.0f / fmaxf(sqrtf(ss), 1e-12f);
                uint2 pk;
                pk.x = f2bf2(sk.x * rinv, sk.y * rinv);
                pk.y = f2bf2(sk.z * rinv, sk.w * rinv);
                *(uint2*)&Ks[p * 40 + d4 * 4] = pk;
                Vts[(d4 * 4 + 0) * 232 + p] = f2h(sv.x);
                Vts[(d4 * 4 + 1) * 232 + p] = f2h(sv.y);
                Vts[(d4 * 4 + 2) * 232 + p] = f2h(sv.z);
                Vts[(d4 * 4 + 3) * 232 + p] = f2h(sv.w);
            }
        }
    }
    // zero V^T pad cols 196..223
    for (int idx = t; idx < 448; idx += 256) {
        int row = (idx * 2341) >> 15;
        int c = idx - row * 14;
        ((unsigned*)(Vts + row * 232))[98 + c] = 0u;
    }

    // ---- own q: dw-conv of this lane's (px, 8ch) B-frag chunk ----
    const int w = t >> 6, lane = t & 63;
    const int lm = lane & 15, lq = lane >> 4;
    const int px = w * 16 + lm;
    const int i = i0 + (px >> 3), j = j0 + (px & 7);
    float qf[8];
    #pragma unroll
    for (int e = 0; e < 8; ++e) qf[e] = bsm[lq * 8 + e];
    #pragma unroll
    for (int di = -1; di <= 1; ++di) {
        int ii = i + di;
        if (ii < 0 || ii > 63) continue;
        #pragma unroll
        for (int dj = -1; dj <= 1; ++dj) {
            int jj = j + dj;
            if (jj < 0 || jj > 63) continue;
            int tap = (di + 1) * 3 + dj + 1;
            size_t off = ((size_t)((ii << 6) + jj) << 5) + lq * 8;
            uint4 xu = *(const uint4*)(qpl + off);
            float4 wa = *(const float4*)&wsm[tap * 32 + lq * 8];
            float4 wb = *(const float4*)&wsm[tap * 32 + lq * 8 + 4];
            qf[0] = fmaf(bflo(xu.x), wa.x, qf[0]);
            qf[1] = fmaf(bfhi(xu.x), wa.y, qf[1]);
            qf[2] = fmaf(bflo(xu.y), wa.z, qf[2]);
            qf[3] = fmaf(bfhi(xu.y), wa.w, qf[3]);
            qf[4] = fmaf(bflo(xu.z), wb.x, qf[4]);
            qf[5] = fmaf(bfhi(xu.z), wb.y, qf[5]);
            qf[6] = fmaf(bflo(xu.w), wb.z, qf[6]);
            qf[7] = fmaf(bfhi(xu.w), wb.w, qf[7]);
        }
    }
    float qs = 0.f;
    #pragma unroll
    for (int e = 0; e < 8; ++e) qs = fmaf(qf[e], qf[e], qs);
    qs += __shfl_xor(qs, 16);
    qs += __shfl_xor(qs, 32);
    float qinv = 1.0f / fmaxf(sqrtf(qs), 1e-12f);
    short8 bq;
    #pragma unroll
    for (int e = 0; e < 8; ++e) bq[e] = (short)f2bf(qf[e] * qinv);
    __syncthreads();

    // ---- QK^T: S^T[nbr][px], 13 n-tiles of 16 nbrs ----
    floatx4 acc[13];
    #pragma unroll
    for (int mt = 0; mt < 13; ++mt) {
        short8 ak = *(const short8*)&Ks[(mt * 16 + lm) * 40 + lq * 8];
        floatx4 z = {0.f, 0.f, 0.f, 0.f};
        acc[mt] = __builtin_amdgcn_mfma_f32_16x16x32_bf16(ak, bq, z, 0, 0, 0);
    }
    __syncthreads();                        // Ks dead; Ps may overwrite

    // ---- mask + bias + softmax ----
    const int si = min(max(i - 3, 0), 57), sj = min(max(j - 3, 0), 57);
    const int vloi = si - r0, vloj = sj - c0;
    const int oi = r0 - i + 6, oj = c0 - j + 6;
    const float th = temp[head];
    float mx = -1e30f;
    #pragma unroll
    for (int mt = 0; mt < 13; ++mt) {
        int nb0 = mt * 16 + lq * 4;
        int rh0 = (nb0 * 2341) >> 15;
        int ch0 = nb0 - rh0 * 14;
        #pragma unroll
        for (int r = 0; r < 4; ++r) {
            int ch = ch0 + r, rh = rh0;
            if (ch >= 14) { ch -= 14; rh += 1; }
            int bidx = (rh + oi) * 13 + (ch + oj);
            float bias = rpbs[max(0, min(168, bidx))];
            bool valid = ((unsigned)(rh - vloi) <= 6u) && ((unsigned)(ch - vloj) <= 6u);
            float s = (acc[mt][r] + bias) * th;
            s = valid ? s : -1e30f;
            acc[mt][r] = s;
            mx = fmaxf(mx, s);
        }
    }
    mx = fmaxf(mx, __shfl_xor(mx, 16));
    mx = fmaxf(mx, __shfl_xor(mx, 32));
    float ssum = 0.f;
    #pragma unroll
    for (int mt = 0; mt < 13; ++mt)
        #pragma unroll
        for (int r = 0; r < 4; ++r) {
            float e = __expf(acc[mt][r] - mx);
            acc[mt][r] = e;
            ssum += e;
        }
    ssum += __shfl_xor(ssum, 16);
    ssum += __shfl_xor(ssum, 32);
    const float rs = 1.0f / ssum;

    if (lane < 32) {                       // zero Ps pad cols 208..223
        uint4 z4 = {0u, 0u, 0u, 0u};
        *(uint4*)&Ps[(w * 16 + (lane >> 1)) * 232 + 208 + (lane & 1) * 8] = z4;
    }
    #pragma unroll
    for (int mt = 0; mt < 13; ++mt) {
        unsigned lo = (unsigned)f2h(acc[mt][0] * rs) | ((unsigned)f2h(acc[mt][1] * rs) << 16);
        unsigned hi = (unsigned)f2h(acc[mt][2] * rs) | ((unsigned)f2h(acc[mt][3] * rs) << 16);
        *(uint2*)&Ps[px * 232 + mt * 16 + lq * 4] = make_uint2(lo, hi);
    }
    __syncthreads();

    // ---- PV: O[px][d] = P x V^T ----
    floatx4 oacc[2] = {};
    #pragma unroll
    for (int ks = 0; ks < 7; ++ks) {
        half8 ap = *(const half8*)&Ps[(w * 16 + lm) * 232 + ks * 32 + lq * 8];
        #pragma unroll
        for (int n2 = 0; n2 < 2; ++n2) {
            half8 bv = *(const half8*)&Vts[(n2 * 16 + lm) * 232 + ks * 32 + lq * 8];
            oacc[n2] = __builtin_amdgcn_mfma_f32_16x16x32_f16(ap, bv, oacc[n2], 0, 0, 0);
        }
    }
    #pragma unroll
    for (int n2 = 0; n2 < 2; ++n2)
        #pragma unroll
        for (int r = 0; r < 4; ++r) {
            int p2 = w * 16 + lq * 4 + r;
            int i2 = i0 + (p2 >> 3), j2 = j0 + (p2 & 7);
            attnO[((size_t)((b << 12) + (i2 << 6) + j2)) * 192 + head * 32 + n2 * 16 + lm]
                = f2bf(oacc[n2][r]);
        }
}

// ---------------------------------------------------------------------------
// K3: proj 1x1 as bf16 MFMA GEMM. M=8192 N=192 K=192. fp32 NCHW out + bias.
// ---------------------------------------------------------------------------
__global__ __launch_bounds__(256) void k_gp(const unsigned short* __restrict__ Ain,
    const unsigned short* __restrict__ Wbp, const float* __restrict__ bp,
    float* __restrict__ out)
{
    __shared__ __align__(16) unsigned short As[64 * 200];
    __shared__ __align__(16) unsigned short Bs[64 * 200];
    const int t = threadIdx.x;
    const int m0 = blockIdx.x * 64;
    const int n0 = blockIdx.y * 64;
    #pragma unroll
    for (int pass = 0; pass < 6; ++pass) {
        int idx = pass * 256 + t;
        int m = idx / 24, c16 = idx % 24;
        *(uint4*)&As[m * 200 + c16 * 8] = *(const uint4*)&Ain[(size_t)(m0 + m) * 192 + c16 * 8];
        *(uint4*)&Bs[m * 200 + c16 * 8] = *(const uint4*)&Wbp[(size_t)(n0 + m) * 192 + c16 * 8];
    }
    __syncthreads();
    const int w = t >> 6, lane = t & 63;
    const int lm = lane & 15, lq = lane >> 4;
    floatx4 acc[4] = {};
    #pragma unroll
    for (int ks = 0; ks < 6; ++ks) {
        short8 bf = *(const short8*)&Bs[(w * 16 + lm) * 200 + ks * 32 + lq * 8];
        #pragma unroll
        for (int mt = 0; mt < 4; ++mt) {
            short8 af = *(const short8*)&As[(mt * 16 + lm) * 200 + ks * 32 + lq * 8];
            acc[mt] = __builtin_amdgcn_mfma_f32_16x16x32_bf16(af, bf, acc[mt], 0, 0, 0);
        }
    }
    __syncthreads();
    float* fs = (float*)As;                 // [n][m] stride 68
    const float bias = bp[n0 + w * 16 + lm];
    #pragma unroll
    for (int mt = 0; mt < 4; ++mt)
        #pragma unroll
        for (int r = 0; r < 4; ++r)
            fs[(w * 16 + lm) * 68 + mt * 16 + lq * 4 + r] = acc[mt][r] + bias;
    __syncthreads();
    const int b = m0 >> 12, px0 = m0 & 4095;
    #pragma unroll
    for (int pass = 0; pass < 4; ++pass) {
        int idx = pass * 256 + t;           // 64 n x 16 m-quads
        int n = idx >> 4, m4 = idx & 15;
        float4 val = *(const float4*)&fs[n * 68 + m4 * 4];
        *(float4*)&out[((size_t)(b * 192 + n0 + n) << 12) + px0 + m4 * 4] = val;
    }
}

extern "C" void kernel_launch(void* const* d_in, const int* in_sizes, int n_in,
                              void* d_out, int out_size, void* d_ws, size_t ws_size,
                              hipStream_t stream) {
    const float* x    = (const float*)d_in[0];
    const float* W1   = (const float*)d_in[1];
    const float* b1   = (const float*)d_in[2];
    const float* W2   = (const float*)d_in[3];
    const float* b2   = (const float*)d_in[4];
    const float* temp = (const float*)d_in[5];
    const float* rpb  = (const float*)d_in[6];
    const float* Wp   = (const float*)d_in[7];
    const float* bp   = (const float*)d_in[8];
    float* out = (float*)d_out;

    char* ws = (char*)d_ws;
    unsigned short* Wb1   = (unsigned short*)(ws);
    unsigned short* Wbp   = (unsigned short*)(ws + 221184);
    unsigned short* xT    = (unsigned short*)(ws + 294912);
    unsigned short* qkv1b = (unsigned short*)(ws + 3440640);
    unsigned short* attnO = (unsigned short*)(ws + 12877824);

    k_prep<<<dim3(960), 256, 0, stream>>>(x, W1, Wp, xT, Wb1, Wbp);
    k_gq  <<<dim3(128, 9), 256, 0, stream>>>(xT, Wb1, b1, qkv1b);
    k_attn<<<dim3(64, 6, 2), 256, 0, stream>>>(qkv1b, W2, b2, temp, rpb, attnO);
    k_gp  <<<dim3(128, 3), 256, 0, stream>>>(attnO, Wbp, bp, out);
}

// Round 7
// 113.246 us; speedup vs baseline: 1.2558x; 1.2558x over previous
//
#include <hip/hip_runtime.h>
#include <math.h>

#define HW 4096

typedef __attribute__((ext_vector_type(8))) short short8;
typedef __attribute__((ext_vector_type(8))) _Float16 half8;
typedef __attribute__((ext_vector_type(4))) float floatx4;

// ---- bf16 helpers (round-to-nearest-even) ----
__device__ inline float bflo(unsigned u) { return __uint_as_float(u << 16); }
__device__ inline float bfhi(unsigned u) { return __uint_as_float(u & 0xffff0000u); }
__device__ inline unsigned short f2bf(float x) {
    unsigned u = __float_as_uint(x);
    return (unsigned short)((u + 0x7fffu + ((u >> 16) & 1u)) >> 16);
}
__device__ inline unsigned f2bf2(float lo, float hi) {
    unsigned a = __float_as_uint(lo), b = __float_as_uint(hi);
    a = (a + 0x7fffu + ((a >> 16) & 1u)) >> 16;
    b = (b + 0x7fffu + ((b >> 16) & 1u)) & 0xffff0000u;
    return a | b;
}
__device__ inline unsigned short f2h(float x) {
    _Float16 h = (_Float16)x;
    return __builtin_bit_cast(unsigned short, h);
}

// ws layout (bytes):
//   qkv1b @ 0        : 2*18*4096*32*2 = 9437184  bf16 [b][g][px][32] (pre-dw)
//   qkv2b @ 9437184  : 9437184                   bf16 (post-dw)
//   attnO @ 18874368 : 2*4096*192*2 = 3145728    bf16 [b*px][c]

// ---------------------------------------------------------------------------
// K1: QKV 1x1 conv as bf16 MFMA GEMM, M=8192(px) N=576(oc) K=192.
// Transpose+convert fused into staging:
//   A: x fp32 [c][px] -> As[px][c] bf16 (wave-row coalesced b32 loads,
//      reg-pack 4c -> one b64 LDS write; stride 200 keeps frag reads b128).
//   B: W1 fp32 [oc][c] -> Bs bf16 (float4 load + packed convert).
// out bf16 [b][g][px][32], bias fused in epilogue.
// ---------------------------------------------------------------------------
__global__ __launch_bounds__(256) void k_gq(const float* __restrict__ x,
    const float* __restrict__ W1, const float* __restrict__ b1,
    unsigned short* __restrict__ qkv)
{
    __shared__ __align__(16) unsigned short As[64 * 200];
    __shared__ __align__(16) unsigned short Bs[64 * 200];
    const int t = threadIdx.x;
    const int m0 = blockIdx.x * 64;
    const int n0 = blockIdx.y * 64;
    const int w = t >> 6, lane = t & 63;
    const int b = m0 >> 12, px0 = m0 & 4095;
    // ---- A: transpose-convert 64px x 192c ----
    {
        const float* xb = x + ((size_t)(b * 192) << 12) + px0 + lane;
        const int cb = w * 48;
        #pragma unroll
        for (int r4 = 0; r4 < 12; ++r4) {
            float v0 = xb[(size_t)(cb + r4 * 4 + 0) << 12];
            float v1 = xb[(size_t)(cb + r4 * 4 + 1) << 12];
            float v2 = xb[(size_t)(cb + r4 * 4 + 2) << 12];
            float v3 = xb[(size_t)(cb + r4 * 4 + 3) << 12];
            *(uint2*)&As[lane * 200 + cb + r4 * 4] =
                make_uint2(f2bf2(v0, v1), f2bf2(v2, v3));
        }
    }
    // ---- B: convert W1 slice [n0..n0+63][192] ----
    #pragma unroll
    for (int pass = 0; pass < 12; ++pass) {
        int idx = pass * 256 + t;
        int row = idx / 48, ch = idx - row * 48;
        float4 wv = *(const float4*)&W1[(size_t)(n0 + row) * 192 + ch * 4];
        *(uint2*)&Bs[row * 200 + ch * 4] =
            make_uint2(f2bf2(wv.x, wv.y), f2bf2(wv.z, wv.w));
    }
    __syncthreads();
    const int lm = lane & 15, lq = lane >> 4;
    floatx4 acc[4] = {};
    #pragma unroll
    for (int ks = 0; ks < 6; ++ks) {
        short8 bf = *(const short8*)&Bs[(w * 16 + lm) * 200 + ks * 32 + lq * 8];
        #pragma unroll
        for (int mt = 0; mt < 4; ++mt) {
            short8 af = *(const short8*)&As[(mt * 16 + lm) * 200 + ks * 32 + lq * 8];
            acc[mt] = __builtin_amdgcn_mfma_f32_16x16x32_bf16(af, bf, acc[mt], 0, 0, 0);
        }
    }
    __syncthreads();
    const float bias = b1[n0 + w * 16 + lm];
    #pragma unroll
    for (int mt = 0; mt < 4; ++mt)
        #pragma unroll
        for (int r = 0; r < 4; ++r)
            As[(mt * 16 + lq * 4 + r) * 72 + w * 16 + lm] = f2bf(acc[mt][r] + bias);
    __syncthreads();
    #pragma unroll
    for (int pass = 0; pass < 2; ++pass) {
        int idx = pass * 256 + t;           // 64 m x 8 n-groups
        int m = idx >> 3, n8 = idx & 7;
        uint4 val = *(const uint4*)&As[m * 72 + n8 * 8];
        int oc = n0 + n8 * 8;
        int g = oc >> 5, d = oc & 31;
        *(uint4*)&qkv[((((size_t)(b * 18 + g) << 12) + px0 + m) << 5) + d] = val;
    }
}

// ---------------------------------------------------------------------------
// K2: depthwise 3x3, bf16 in/out, fp32 math, weights staged in LDS.
// ---------------------------------------------------------------------------
__global__ __launch_bounds__(256) void k_dw(const unsigned short* __restrict__ in,
    const float* __restrict__ W2, const float* __restrict__ b2,
    unsigned short* __restrict__ outq)
{
    __shared__ float wsm[288];
    __shared__ float bsm[32];
    const int t = threadIdx.x;
    const int bg = blockIdx.y;
    const int g = (bg >= 18) ? bg - 18 : bg;
    const int cbase = (g / 6) * 192 + (g % 6) * 32;
    for (int idx = t; idx < 288; idx += 256)
        wsm[idx] = W2[(cbase + (idx & 31)) * 9 + (idx >> 5)];
    if (t < 32) bsm[t] = b2[cbase + t];
    __syncthreads();
    const int px = (blockIdx.x << 6) + (t >> 2);
    const int d8 = t & 3;
    const int i = px >> 6, j = px & 63;
    const unsigned short* base = in + ((size_t)bg << 17);
    float acc[8];
    #pragma unroll
    for (int e = 0; e < 8; ++e) acc[e] = bsm[d8 * 8 + e];
    #pragma unroll
    for (int di = -1; di <= 1; ++di) {
        int ii = i + di;
        if (ii < 0 || ii > 63) continue;
        #pragma unroll
        for (int dj = -1; dj <= 1; ++dj) {
            int jj = j + dj;
            if (jj < 0 || jj > 63) continue;
            int tap = (di + 1) * 3 + dj + 1;
            uint4 u = *(const uint4*)(base + ((((ii << 6) + jj) << 5) + d8 * 8));
            const float* wt = &wsm[tap * 32 + d8 * 8];
            acc[0] = fmaf(bflo(u.x), wt[0], acc[0]);
            acc[1] = fmaf(bfhi(u.x), wt[1], acc[1]);
            acc[2] = fmaf(bflo(u.y), wt[2], acc[2]);
            acc[3] = fmaf(bfhi(u.y), wt[3], acc[3]);
            acc[4] = fmaf(bflo(u.z), wt[4], acc[4]);
            acc[5] = fmaf(bfhi(u.z), wt[5], acc[5]);
            acc[6] = fmaf(bflo(u.w), wt[6], acc[6]);
            acc[7] = fmaf(bfhi(u.w), wt[7], acc[7]);
        }
    }
    uint4 o;
    o.x = f2bf2(acc[0], acc[1]); o.y = f2bf2(acc[2], acc[3]);
    o.z = f2bf2(acc[4], acc[5]); o.w = f2bf2(acc[6], acc[7]);
    *(uint4*)(outq + ((size_t)bg << 17) + ((size_t)px << 5) + d8 * 8) = o;
}

// ---------------------------------------------------------------------------
// K3: MFMA neighborhood attention (R5 structure, unfused dw).
// Block 256 = (b, head, 8x8 tile), 4 waves. S^T = K-hat x q-hat^T (mfma bf16),
// mask+bias+softmax in regs, P f16 -> LDS (aliases Ks), PV via mfma f16.
// ---------------------------------------------------------------------------
__global__ __launch_bounds__(256) void k_attn(const unsigned short* __restrict__ qkv,
    const float* __restrict__ temp, const float* __restrict__ rpb,
    unsigned short* __restrict__ attnO)
{
    __shared__ __align__(16) char lds[45224];
    unsigned short* Ks  = (unsigned short*)lds;            // [208][40] bf16
    unsigned short* Ps  = (unsigned short*)lds;            // [64][232] f16 (alias)
    unsigned short* Vts = (unsigned short*)(lds + 29696);  // [32][232] f16
    float* rpbs = (float*)(lds + 44544);                   // [169]

    const int t = threadIdx.x;
    const int ti = blockIdx.x >> 3, tj = blockIdx.x & 7;
    const int head = blockIdx.y, b = blockIdx.z;
    const int i0 = ti * 8, j0 = tj * 8;
    const int r0 = min(max(i0 - 3, 0), 50), c0 = min(max(j0 - 3, 0), 50);
    const unsigned short* qpl = qkv + ((size_t)(b * 18 + head) << 17);
    const unsigned short* kpl = qkv + ((size_t)(b * 18 + 6 + head) << 17);
    const unsigned short* vpl = qkv + ((size_t)(b * 18 + 12 + head) << 17);

    // ---- stage K-hat (bf16, l2-normalized) and V^T (f16) ----
    if (t < 196) {
        int r = (t * 2341) >> 15, cc = t - r * 14;
        int pix = ((r0 + r) << 6) + (c0 + cc);
        const uint4* kg = (const uint4*)(kpl + (pix << 5));
        const uint4* vg = (const uint4*)(vpl + (pix << 5));
        float kf[32];
        float ss = 0.f;
        #pragma unroll
        for (int q = 0; q < 4; ++q) {
            uint4 ku = kg[q];
            unsigned uu[4] = {ku.x, ku.y, ku.z, ku.w};
            #pragma unroll
            for (int e = 0; e < 4; ++e) {
                float lo = bflo(uu[e]), hi = bfhi(uu[e]);
                kf[q * 8 + e * 2] = lo; kf[q * 8 + e * 2 + 1] = hi;
                ss = fmaf(lo, lo, fmaf(hi, hi, ss));
            }
        }
        float rinv = 1.0f / fmaxf(sqrtf(ss), 1e-12f);
        #pragma unroll
        for (int q = 0; q < 4; ++q) {
            uint4 p;
            p.x = f2bf2(kf[q * 8 + 0] * rinv, kf[q * 8 + 1] * rinv);
            p.y = f2bf2(kf[q * 8 + 2] * rinv, kf[q * 8 + 3] * rinv);
            p.z = f2bf2(kf[q * 8 + 4] * rinv, kf[q * 8 + 5] * rinv);
            p.w = f2bf2(kf[q * 8 + 6] * rinv, kf[q * 8 + 7] * rinv);
            *(uint4*)&Ks[t * 40 + q * 8] = p;
        }
        #pragma unroll
        for (int q = 0; q < 4; ++q) {
            uint4 vu = vg[q];
            unsigned uu[4] = {vu.x, vu.y, vu.z, vu.w};
            #pragma unroll
            for (int e = 0; e < 4; ++e) {
                Vts[(q * 8 + e * 2) * 232 + t]     = f2h(bflo(uu[e]));
                Vts[(q * 8 + e * 2 + 1) * 232 + t] = f2h(bfhi(uu[e]));
            }
        }
    }
    // zero V^T cols 196..223 (PV pad region must be 0)
    for (int idx = t; idx < 448; idx += 256) {
        int row = (idx * 2341) >> 15;
        int c = idx - row * 14;
        ((unsigned*)(Vts + row * 232))[98 + c] = 0u;
    }
    if (t < 169) rpbs[t] = rpb[head * 169 + t];

    // ---- q-hat fragment in registers ----
    const int w = t >> 6, lane = t & 63;
    const int lm = lane & 15, lq = lane >> 4;
    const int px = w * 16 + lm;
    const int i = i0 + (px >> 3), j = j0 + (px & 7);
    uint4 qu = *(const uint4*)(qpl + ((((i << 6) + j) << 5) + lq * 8));
    float qf[8];
    qf[0] = bflo(qu.x); qf[1] = bfhi(qu.x);
    qf[2] = bflo(qu.y); qf[3] = bfhi(qu.y);
    qf[4] = bflo(qu.z); qf[5] = bfhi(qu.z);
    qf[6] = bflo(qu.w); qf[7] = bfhi(qu.w);
    float qs = 0.f;
    #pragma unroll
    for (int e = 0; e < 8; ++e) qs = fmaf(qf[e], qf[e], qs);
    qs += __shfl_xor(qs, 16);
    qs += __shfl_xor(qs, 32);
    float qinv = 1.0f / fmaxf(sqrtf(qs), 1e-12f);
    short8 bq;
    #pragma unroll
    for (int e = 0; e < 8; ++e) bq[e] = (short)f2bf(qf[e] * qinv);
    __syncthreads();

    // ---- QK^T: S^T[nbr][px], 13 n-tiles of 16 nbrs ----
    floatx4 acc[13];
    #pragma unroll
    for (int mt = 0; mt < 13; ++mt) {
        short8 ak = *(const short8*)&Ks[(mt * 16 + lm) * 40 + lq * 8];
        floatx4 z = {0.f, 0.f, 0.f, 0.f};
        acc[mt] = __builtin_amdgcn_mfma_f32_16x16x32_bf16(ak, bq, z, 0, 0, 0);
    }
    __syncthreads();                        // Ks dead; Ps may overwrite

    // ---- mask + bias + softmax ----
    const int si = min(max(i - 3, 0), 57), sj = min(max(j - 3, 0), 57);
    const int vloi = si - r0, vloj = sj - c0;
    const int oi = r0 - i + 6, oj = c0 - j + 6;
    const float th = temp[head];
    float mx = -1e30f;
    #pragma unroll
    for (int mt = 0; mt < 13; ++mt) {
        int nb0 = mt * 16 + lq * 4;
        int rh0 = (nb0 * 2341) >> 15;
        int ch0 = nb0 - rh0 * 14;
        #pragma unroll
        for (int r = 0; r < 4; ++r) {
            int ch = ch0 + r, rh = rh0;
            if (ch >= 14) { ch -= 14; rh += 1; }
            int bidx = (rh + oi) * 13 + (ch + oj);
            float bias = rpbs[max(0, min(168, bidx))];
            bool valid = ((unsigned)(rh - vloi) <= 6u) && ((unsigned)(ch - vloj) <= 6u);
            float s = (acc[mt][r] + bias) * th;
            s = valid ? s : -1e30f;
            acc[mt][r] = s;
            mx = fmaxf(mx, s);
        }
    }
    mx = fmaxf(mx, __shfl_xor(mx, 16));
    mx = fmaxf(mx, __shfl_xor(mx, 32));
    float ssum = 0.f;
    #pragma unroll
    for (int mt = 0; mt < 13; ++mt)
        #pragma unroll
        for (int r = 0; r < 4; ++r) {
            float e = __expf(acc[mt][r] - mx);
            acc[mt][r] = e;
            ssum += e;
        }
    ssum += __shfl_xor(ssum, 16);
    ssum += __shfl_xor(ssum, 32);
    const float rs = 1.0f / ssum;

    if (lane < 32) {                       // zero Ps pad cols 208..223
        uint4 z4 = {0u, 0u, 0u, 0u};
        *(uint4*)&Ps[(w * 16 + (lane >> 1)) * 232 + 208 + (lane & 1) * 8] = z4;
    }
    #pragma unroll
    for (int mt = 0; mt < 13; ++mt) {
        unsigned lo = (unsigned)f2h(acc[mt][0] * rs) | ((unsigned)f2h(acc[mt][1] * rs) << 16);
        unsigned hi = (unsigned)f2h(acc[mt][2] * rs) | ((unsigned)f2h(acc[mt][3] * rs) << 16);
        *(uint2*)&Ps[px * 232 + mt * 16 + lq * 4] = make_uint2(lo, hi);
    }
    __syncthreads();

    // ---- PV: O[px][d] = P x V^T ----
    floatx4 oacc[2] = {};
    #pragma unroll
    for (int ks = 0; ks < 7; ++ks) {
        half8 ap = *(const half8*)&Ps[(w * 16 + lm) * 232 + ks * 32 + lq * 8];
        #pragma unroll
        for (int n2 = 0; n2 < 2; ++n2) {
            half8 bv = *(const half8*)&Vts[(n2 * 16 + lm) * 232 + ks * 32 + lq * 8];
            oacc[n2] = __builtin_amdgcn_mfma_f32_16x16x32_f16(ap, bv, oacc[n2], 0, 0, 0);
        }
    }
    #pragma unroll
    for (int n2 = 0; n2 < 2; ++n2)
        #pragma unroll
        for (int r = 0; r < 4; ++r) {
            int p2 = w * 16 + lq * 4 + r;
            int i2 = i0 + (p2 >> 3), j2 = j0 + (p2 & 7);
            attnO[((size_t)((b << 12) + (i2 << 6) + j2)) * 192 + head * 32 + n2 * 16 + lm]
                = f2bf(oacc[n2][r]);
        }
}

// ---------------------------------------------------------------------------
// K4: proj 1x1 as bf16 MFMA GEMM. M=8192 N=192 K=192. Wp converted fp32->bf16
// in staging. fp32 NCHW out + bias.
// ---------------------------------------------------------------------------
__global__ __launch_bounds__(256) void k_gp(const unsigned short* __restrict__ Ain,
    const float* __restrict__ Wp, const float* __restrict__ bp,
    float* __restrict__ out)
{
    __shared__ __align__(16) unsigned short As[64 * 200];
    __shared__ __align__(16) unsigned short Bs[64 * 200];
    const int t = threadIdx.x;
    const int m0 = blockIdx.x * 64;
    const int n0 = blockIdx.y * 64;
    #pragma unroll
    for (int pass = 0; pass < 6; ++pass) {
        int idx = pass * 256 + t;
        int m = idx / 24, c16 = idx % 24;
        *(uint4*)&As[m * 200 + c16 * 8] = *(const uint4*)&Ain[(size_t)(m0 + m) * 192 + c16 * 8];
    }
    #pragma unroll
    for (int pass = 0; pass < 12; ++pass) {
        int idx = pass * 256 + t;
        int row = idx / 48, ch = idx - row * 48;
        float4 wv = *(const float4*)&Wp[(size_t)(n0 + row) * 192 + ch * 4];
        *(uint2*)&Bs[row * 200 + ch * 4] =
            make_uint2(f2bf2(wv.x, wv.y), f2bf2(wv.z, wv.w));
    }
    __syncthreads();
    const int w = t >> 6, lane = t & 63;
    const int lm = lane & 15, lq = lane >> 4;
    floatx4 acc[4] = {};
    #pragma unroll
    for (int ks = 0; ks < 6; ++ks) {
        short8 bf = *(const short8*)&Bs[(w * 16 + lm) * 200 + ks * 32 + lq * 8];
        #pragma unroll
        for (int mt = 0; mt < 4; ++mt) {
            short8 af = *(const short8*)&As[(mt * 16 + lm) * 200 + ks * 32 + lq * 8];
            acc[mt] = __builtin_amdgcn_mfma_f32_16x16x32_bf16(af, bf, acc[mt], 0, 0, 0);
        }
    }
    __syncthreads();
    float* fs = (float*)As;                 // [n][m] stride 68
    const float bias = bp[n0 + w * 16 + lm];
    #pragma unroll
    for (int mt = 0; mt < 4; ++mt)
        #pragma unroll
        for (int r = 0; r < 4; ++r)
            fs[(w * 16 + lm) * 68 + mt * 16 + lq * 4 + r] = acc[mt][r] + bias;
    __syncthreads();
    const int b = m0 >> 12, px0 = m0 & 4095;
    #pragma unroll
    for (int pass = 0; pass < 4; ++pass) {
        int idx = pass * 256 + t;           // 64 n x 16 m-quads
        int n = idx >> 4, m4 = idx & 15;
        float4 val = *(const float4*)&fs[n * 68 + m4 * 4];
        *(float4*)&out[((size_t)(b * 192 + n0 + n) << 12) + px0 + m4 * 4] = val;
    }
}

extern "C" void kernel_launch(void* const* d_in, const int* in_sizes, int n_in,
                              void* d_out, int out_size, void* d_ws, size_t ws_size,
                              hipStream_t stream) {
    const float* x    = (const float*)d_in[0];
    const float* W1   = (const float*)d_in[1];
    const float* b1   = (const float*)d_in[2];
    const float* W2   = (const float*)d_in[3];
    const float* b2   = (const float*)d_in[4];
    const float* temp = (const float*)d_in[5];
    const float* rpb  = (const float*)d_in[6];
    const float* Wp   = (const float*)d_in[7];
    const float* bp   = (const float*)d_in[8];
    float* out = (float*)d_out;

    char* ws = (char*)d_ws;
    unsigned short* qkv1b = (unsigned short*)(ws);
    unsigned short* qkv2b = (unsigned short*)(ws + 9437184);
    unsigned short* attnO = (unsigned short*)(ws + 18874368);

    k_gq  <<<dim3(128, 9), 256, 0, stream>>>(x, W1, b1, qkv1b);
    k_dw  <<<dim3(64, 36), 256, 0, stream>>>(qkv1b, W2, b2, qkv2b);
    k_attn<<<dim3(64, 6, 2), 256, 0, stream>>>(qkv2b, temp, rpb, attnO);
    k_gp  <<<dim3(128, 3), 256, 0, stream>>>(attnO, Wp, bp, out);
}